// Round 4
// baseline (195.214 us; speedup 1.0000x reference)
//
#include <hip/hip_runtime.h>
#include <cstdint>

// Problem constants (from the reference)
#define LL    200
#define QQ    21
#define MM    1024
#define START 133        // 2*L//3
#define NS    67         // L - START
#define RGH   0.01f
#define RGJ   0.01f

// ws layout:
//   [0, 1024)              : accumulator slots (3 x 64 fp32)
//   [1024, +TOKP)          : tokP packed tokens, 4 j per dword, [jq][n]
//                            (52 words: 50 real + 2 pad, pad never consumed)
//   [TOKP end, +SLAB)      : logit slab [iI][a][n], atomic-accumulated
#define SLOT_J2  0
#define SLOT_E   64
#define SLOT_LZ  128
#define TOKP_W   52
#define TOKP_OFF 1024
#define TOKP_BYTES ((size_t)TOKP_W * MM * 4)
#define SLAB_OFF (TOKP_OFF + TOKP_BYTES)
#define SLAB_FLOATS ((size_t)NS * QQ * MM)
#define SLAB_BYTES (SLAB_FLOATS * 4)
#define WS_FULL (SLAB_OFF + SLAB_BYTES)
#define WS_TOK  SLAB_OFF

// LDS tile: raw a-major copy of J[i, a, j0:j0+TJ, :]. TJ=8 -> plane = 168
// dwords (672 B = exactly 42 16B chunks):
//  - DMA: 42-lane global_load_lds(16B) fills a plane exactly
//  - gather: ds_read2_b32 pairs planes (a, a+1): dword offsets 0/168 fit the
//    8-bit read2 fields. Lanes differ only in b -> <=21 consecutive dwords
//    -> conflict-free (measured 0 conflicts).
// NBUF=3 x 14112 B = 42336 B/block -> 3 blocks/CU (2 p1 + 1 jsum filler).
// R3 lesson: ONE barrier-synced p1 block per CU runs at ~1280 cyc/j (own
// stalls exposed); two co-resident p1 blocks mutually fill stalls (R2
// measured 681 cyc/j). This round restores 2 p1 blocks/CU at equal load.
#define TJ 8
#define PLANE 168
#define TILE_FLOATS (QQ * PLANE)       // 3528 floats = 14112 B
#define NBUF 3
#define BT 512
#define NWAVE 8

// Balanced p1 schedule: flatten (site, j-quad) -> [0, Tz) cut into NB_R
// equal ranges (~11 quads); block bx = (range bx&255, z-half bx>>8).
// Blocks bx and bx+256 land on the same CU (round-robin dispatch) and DMA
// IDENTICAL J tiles -> L1/L2-hot staging. A range (<=11 quads) spans <=2
// sites (site >= 34 quads); partial sums atomicAdd-flush into slab.
#define NB_R  256
#define NB_P1 (2 * NB_R)               // 512
#define NB_JS 512
#define NB_TOKP 512

typedef const uint32_t __attribute__((address_space(1)))* gq_t;
typedef uint32_t __attribute__((address_space(3)))* lq_t;

template <int NW>
__device__ __forceinline__ float block_reduce_sum(float v) {
  __shared__ float sm[NW];
  #pragma unroll
  for (int off = 32; off > 0; off >>= 1) v += __shfl_down(v, off, 64);
  const int lane = threadIdx.x & 63;
  const int wv   = threadIdx.x >> 6;
  __syncthreads();
  if (lane == 0) sm[wv] = v;
  __syncthreads();
  float r = 0.0f;
  if (threadIdx.x == 0) {
    #pragma unroll
    for (int k = 0; k < NW; ++k) r += sm[k];
  }
  return r;  // valid in thread 0 only
}

// ---------------------------------------------------------------------------
// DMA one tile (21 a-planes) into LDS. Wave wv owns planes {wv, wv+8, wv+16}:
// waves 0-4 issue 3 global_load_lds, waves 5-7 issue 2 (lane guard keeps
// active lanes in every wave, so per-wave vmem counts are exact).
// Fake tiles pass rem=1 (6 lanes) to keep counts uniform cheaply.
// ---------------------------------------------------------------------------
__device__ __forceinline__ void dma_tile(
    const float* __restrict__ Ji, int j0, int rem, int wv, int lane,
    float* __restrict__ tile) {
  const int nlanes = (rem * QQ + 3) >> 2;      // 42 for rem=8; >=6 always
  if (lane < nlanes) {
    for (int a = wv; a < QQ; a += NWAVE) {
      const float* g = Ji + a * (LL * QQ) + j0 * QQ + lane * 4;
      __builtin_amdgcn_global_load_lds((gq_t)g, (lq_t)(tile + a * PLANE),
                                       16, 0, 0);
    }
  }
}

// ---------------------------------------------------------------------------
// Load the 2 packed token words covering tile at j0 (8 j's, j0 % 4 == 0).
// Always exactly 2 vmem instructions. Fully-fake tiles reload tile-0 words.
// ---------------------------------------------------------------------------
template <int USET>
__device__ __forceinline__ void tok_words(
    const uint32_t* __restrict__ tokP, const int* __restrict__ Xtok,
    int j0, int jbeg, int jend, int n, uint32_t (&tw)[2]) {
  const int wbase = ((j0 < jend) ? j0 : jbeg) >> 2;
  #pragma unroll
  for (int wi = 0; wi < 2; ++wi) {
    int wq = wbase + wi;
    if constexpr (USET) {
      tw[wi] = tokP[wq * MM + n];        // words 50/51 = pad, never consumed
    } else {
      if (wq >= LL / 4) wq -= (LL / 4 - 1);   // keep in-bounds, distinct
      const int4 x = *reinterpret_cast<const int4*>(Xtok + n * LL + 4 * wq);
      tw[wi] = (uint32_t)x.x | ((uint32_t)x.y << 8)
             | ((uint32_t)x.z << 16) | ((uint32_t)x.w << 24);
    }
  }
}

// Counted-wait barrier. Per-iteration vmem per wave = dma (3 or 2) + 2 tok
// = 5/4: waiting vmcnt(5)/vmcnt(4) drains ALL prior-iteration vmem
// (regardless of intra-iteration issue order) while keeping this iteration's
// dma(s+2)+tok(s+2) in flight across the barrier (depth-2 pipeline).
__device__ __forceinline__ void tile_barrier(int wv) {
  if (wv < 5) asm volatile("s_waitcnt vmcnt(5)" ::: "memory");
  else        asm volatile("s_waitcnt vmcnt(4)" ::: "memory");
  __builtin_amdgcn_s_barrier();
  __builtin_amdgcn_sched_barrier(0);
}

// ---------------------------------------------------------------------------
// One pipelined segment: accumulate lg[a] += J[i,a,j,b(n,j)] over
// j in [jbeg, jend), jbeg % 4 == 0. Triple-buffered DMA, depth-2 token
// prefetch, gather via ds_read2_b32 plane-pairs.
// ---------------------------------------------------------------------------
template <int USET>
__device__ __forceinline__ void logz_seg(
    const float* __restrict__ Ji, const uint32_t* __restrict__ tokP,
    const int* __restrict__ Xtok, int jbeg, int jend, int n,
    float (*lds)[TILE_FLOATS], float (&lg)[QQ], int wv, int lane) {
  const int ntiles = (jend - jbeg + TJ - 1) / TJ;   // >= 1
  uint32_t tw0[2], twc[2], twn[2];
  int bo[TJ];

  // Prologue: dma tiles 0,1 (tile1 may be fake), token words tiles 0,1,
  // bo(tile0). One full drain per segment, then counted waits only.
  dma_tile(Ji, jbeg, min(TJ, jend - jbeg), wv, lane, lds[0]);
  { int j1 = jbeg + TJ, r1 = jend - j1;
    if (r1 <= 0) { j1 = jbeg; r1 = 1; } else if (r1 > TJ) r1 = TJ;
    dma_tile(Ji, j1, r1, wv, lane, lds[1]); }
  tok_words<USET>(tokP, Xtok, jbeg, jbeg, jend, n, tw0);
  tok_words<USET>(tokP, Xtok, jbeg + TJ, jbeg, jend, n, twc);
  #pragma unroll
  for (int k = 0; k < TJ; ++k)
    bo[k] = k * QQ + (int)((tw0[k >> 2] >> ((k & 3) * 8)) & 0xFF);
  asm volatile("s_waitcnt vmcnt(0)" ::: "memory");
  __builtin_amdgcn_s_barrier();
  __builtin_amdgcn_sched_barrier(0);

  int cur = 0;
  for (int s = 0; s < ntiles; ++s) {
    const int j0  = jbeg + s * TJ;
    const int rem = min(TJ, jend - j0);
    // dma tile s+2 (fake rem=1 past-the-end keeps per-wave counts uniform)
    { int j2 = j0 + 2 * TJ, r2 = jend - j2;
      if (r2 <= 0) { j2 = jbeg; r2 = 1; } else if (r2 > TJ) r2 = TJ;
      int nb = cur + 2; if (nb >= NBUF) nb -= NBUF;
      dma_tile(Ji, j2, r2, wv, lane, lds[nb]); }
    // token words for tile s+2 (exactly 2 loads)
    tok_words<USET>(tokP, Xtok, j0 + 2 * TJ, jbeg, jend, n, twn);
    // gather tile s: per j, 10 x ds_read2_b32 (plane pairs) + 1 x ds_read_b32
    const float* tile = lds[cur];
    #pragma unroll
    for (int jl = 0; jl < TJ; ++jl) {
      if (jl >= rem) break;            // block-uniform
      const float* p = tile + bo[jl];
      #pragma unroll
      for (int k = 0; k < 10; ++k) {
        int o = k * 2 * PLANE;
        asm("" : "+v"(o));             // opaque offset -> forces read2 fuse 0/168
        const float x = p[o], y = p[o + PLANE];
        lg[2 * k]     += x;
        lg[2 * k + 1] += y;
      }
      lg[20] += p[20 * PLANE];         // odd plane: imm-offset b32
    }
    // unpack bo for tile s+1 (words loaded LAST iteration); shift prefetch
    #pragma unroll
    for (int k = 0; k < TJ; ++k)
      bo[k] = k * QQ + (int)((twc[k >> 2] >> ((k & 3) * 8)) & 0xFF);
    #pragma unroll
    for (int wi = 0; wi < 2; ++wi) twc[wi] = twn[wi];
    tile_barrier(wv);                  // counted wait — NO vmcnt(0) drain
    ++cur; if (cur == NBUF) cur = 0;
  }
}

// ---------------------------------------------------------------------------
// p1 block: balanced quad-schedule per z-half. Block = (range r, z); range r
// owns quads [r*Tz/NB_R, (r+1)*Tz/NB_R) of the flattened (site, quad) space;
// runs <=2 segments, atomic-flushing lg into slab[site][a][n]. Blocks
// (r, z=0) and (r, z=1) co-reside on a CU and DMA identical J tiles.
// ---------------------------------------------------------------------------
__device__ __forceinline__ void p1_block(
    const float* __restrict__ J, const uint32_t* __restrict__ tokP,
    float* __restrict__ slab, int bx, float (*lds)[TILE_FLOATS]) {
  const int t = threadIdx.x, lane = t & 63, wv = t >> 6;
  const int r = bx & (NB_R - 1);
  const int z = bx >> 8;

  int Tz = 0;                          // constant-folds (NS, START constants)
  #pragma unroll
  for (int s2 = 0; s2 < NS; ++s2) Tz += (START + s2 + 3) >> 2;

  int g  = (r * Tz) / NB_R;
  const int g1 = ((r + 1) * Tz) / NB_R;
  int iI = 0, pref = 0;
  while (pref + ((START + iI + 3) >> 2) <= g) {
    pref += (START + iI + 3) >> 2;
    ++iI;
  }
  int qlo = g - pref;

  float lg[QQ];
  #pragma unroll
  for (int a = 0; a < QQ; ++a) lg[a] = 0.0f;

  while (g < g1) {
    const int i    = START + iI;
    const int qcap = (i + 3) >> 2;
    int qhi = qlo + (g1 - g);
    if (qhi > qcap) qhi = qcap;
    const int jbeg = qlo * 4;
    int jend = qhi * 4; if (jend > i) jend = i;
    const int n = z * BT + t;
    const float* Ji = J + (size_t)i * (QQ * LL * QQ);

    logz_seg<1>(Ji, tokP, nullptr, jbeg, jend, n, lds, lg, wv, lane);

    float* dst = slab + ((size_t)iI * QQ) * MM + n;
    #pragma unroll
    for (int a = 0; a < QQ; ++a) { atomicAdd(dst + a * MM, lg[a]); lg[a] = 0.0f; }

    g += qhi - qlo;
    qlo = 0; ++iI;
  }
}

// ---------------------------------------------------------------------------
// jsum body: sum(J^2) stream + sum(J*fij) prefix rows, grid-strided by jb.
// ---------------------------------------------------------------------------
__device__ __forceinline__ void jsum_body(
    const float* __restrict__ J, const float* __restrict__ fij,
    float* __restrict__ acc, int jb) {
  const int t = threadIdx.x;
  const float4* __restrict__ J4 = (const float4*)J;
  float j2 = 0.0f;
  for (int f = jb * BT + t; f < (LL * QQ * LL * QQ / 4); f += NB_JS * BT) {
    const float4 v = J4[f];
    j2 += v.x * v.x + v.y * v.y + v.z * v.z + v.w * v.w;
  }
  float e = 0.0f;
  for (int r = jb; r < NS * QQ; r += NB_JS) {
    const int iI = r / QQ;
    const int a  = r - iI * QQ;
    const int i  = START + iI;
    const size_t base = (size_t)i * (QQ * LL * QQ) + (size_t)a * (LL * QQ);
    const float4* __restrict__ Jb = (const float4*)(J + base);
    const float4* __restrict__ Fb = (const float4*)(fij + base);
    const int lim  = i * QQ;
    const int lim4 = lim >> 2;
    for (int f = t; f < lim4; f += BT) {
      const float4 v = Jb[f], u = Fb[f];
      e += v.x * u.x + v.y * u.y + v.z * u.z + v.w * u.w;
    }
    const int rem = lim & 3;
    if (t < rem) {
      const int p = lim4 * 4 + t;
      e += (J + base)[p] * (fij + base)[p];
    }
  }
  const float tj2 = block_reduce_sum<NWAVE>(j2);
  const float te  = block_reduce_sum<NWAVE>(e);
  if (t == 0) {
    atomicAdd(acc + SLOT_J2 + (jb & 63), tj2);
    atomicAdd(acc + SLOT_E  + (jb & 63), te);
  }
}

// ---------------------------------------------------------------------------
// Fused kernel: blocks [0, NB_P1) run p1 (2 co-resident per CU, mutually
// stall-hiding); blocks [NB_P1, NB_P1+NB_JS) run jsum (HBM-bound fillers)
// on each CU's 3rd block slot + the makespan tail.
// ---------------------------------------------------------------------------
__global__ __launch_bounds__(BT) void kern_mega(
    const float* __restrict__ J, const float* __restrict__ fij,
    const uint32_t* __restrict__ tokP, float* __restrict__ slab,
    float* __restrict__ acc) {
  __shared__ float lds[NBUF][TILE_FLOATS];
  const int bx = blockIdx.x;
  if (bx < NB_P1) p1_block(J, tokP, slab, bx, lds);
  else            jsum_body(J, fij, acc, bx - NB_P1);
}

// ---------------------------------------------------------------------------
// Fallback (ws too small for slab): full-range mono blocks with in-kernel
// logsumexp. Grid (NS, 1, 2), z = blockIdx.z.
// ---------------------------------------------------------------------------
template <int USET>
__device__ __forceinline__ void mono_body(
    const float* __restrict__ J, const uint32_t* __restrict__ tokP,
    const int* __restrict__ Xtok, const float* __restrict__ h,
    const float* __restrict__ w, float* __restrict__ acc,
    float (*lds)[TILE_FLOATS]) {
  const int iI = blockIdx.x;
  const int i  = START + iI;
  const int t = threadIdx.x, lane = t & 63, wv = t >> 6;
  const int n = blockIdx.z * BT + t;
  float lg[QQ];
  #pragma unroll
  for (int a = 0; a < QQ; ++a) lg[a] = 0.0f;
  logz_seg<USET>(J + (size_t)i * (QQ * LL * QQ), tokP, Xtok, 0, i, n,
                 lds, lg, wv, lane);
  const float* hi = h + i * QQ;
  float mx = -3.0e38f;
  #pragma unroll
  for (int a = 0; a < QQ; ++a) { lg[a] += hi[a]; mx = fmaxf(mx, lg[a]); }
  float sme = 0.0f;
  #pragma unroll
  for (int a = 0; a < QQ; ++a) sme += expf(lg[a] - mx);
  const float contrib = w[n] * (mx + logf(sme));
  const float tot = block_reduce_sum<NWAVE>(contrib);
  if (t == 0) atomicAdd(acc + SLOT_LZ + (iI & 63), tot);
}

__global__ __launch_bounds__(BT) void kern_logz_mono_t(
    const float* __restrict__ J, const uint32_t* __restrict__ tokP,
    const float* __restrict__ h, const float* __restrict__ w,
    float* __restrict__ acc) {
  __shared__ float lds[NBUF][TILE_FLOATS];
  mono_body<1>(J, tokP, nullptr, h, w, acc, lds);
}

__global__ __launch_bounds__(BT) void kern_logz_mono_x(
    const float* __restrict__ J, const int* __restrict__ Xtok,
    const float* __restrict__ h, const float* __restrict__ w,
    float* __restrict__ acc) {
  __shared__ float lds[NBUF][TILE_FLOATS];
  mono_body<0>(J, nullptr, Xtok, h, w, acc, lds);
}

__global__ __launch_bounds__(BT) void kern_jsum(
    const float* __restrict__ J, const float* __restrict__ fij,
    float* __restrict__ acc) {
  jsum_body(J, fij, acc, blockIdx.x);
}

// ---------------------------------------------------------------------------
// Phase 2: slab + h -> logsumexp -> weighted sum (fence-free).
// ---------------------------------------------------------------------------
__global__ __launch_bounds__(128) void kern_logz_p2(
    const float* __restrict__ slab, const float* __restrict__ h,
    const float* __restrict__ w, float* __restrict__ acc) {
  const int iI = blockIdx.x;
  const int n  = blockIdx.y * 128 + threadIdx.x;
  const float* s0 = slab + ((size_t)iI * QQ) * MM + n;
  const float* hi = h + (START + iI) * QQ;
  float lg[QQ];
  float mx = -3.0e38f;
  #pragma unroll
  for (int a = 0; a < QQ; ++a) {
    lg[a] = s0[a * MM] + hi[a];
    mx = fmaxf(mx, lg[a]);
  }
  float sme = 0.0f;
  #pragma unroll
  for (int a = 0; a < QQ; ++a) sme += expf(lg[a] - mx);
  float v = w[n] * (mx + logf(sme));
  #pragma unroll
  for (int off = 32; off > 0; off >>= 1) v += __shfl_down(v, off, 64);
  __shared__ float sm[2];
  if ((threadIdx.x & 63) == 0) sm[threadIdx.x >> 6] = v;
  __syncthreads();
  if (threadIdx.x == 0)
    atomicAdd(acc + SLOT_LZ + ((iI * 8 + blockIdx.y) & 63), sm[0] + sm[1]);
}

// ---------------------------------------------------------------------------
// Token packing: tokP[jq][n] = X[n][4jq..4jq+3] packed as 4 bytes. Block 0
// zeroes the accumulator slots; all blocks grid-stride-zero the slab
// (atomic-accumulated in mega, so it must start at 0).
// ---------------------------------------------------------------------------
__global__ __launch_bounds__(256) void kern_tokP(
    const int* __restrict__ X, uint32_t* __restrict__ tokP,
    float* __restrict__ slab, float* __restrict__ acc, int zslab) {
  const int idx = blockIdx.x * 256 + threadIdx.x;
  if (blockIdx.x == 0) acc[threadIdx.x] = 0.0f;
  if (idx < (LL / 4) * MM) {
    const int jq = idx / MM;
    const int n  = idx - jq * MM;
    const int4 x = *reinterpret_cast<const int4*>(X + n * LL + 4 * jq);
    tokP[idx] = (uint32_t)x.x | ((uint32_t)x.y << 8)
              | ((uint32_t)x.z << 16) | ((uint32_t)x.w << 24);
  }
  if (zslab) {
    float4* s4 = (float4*)slab;
    const int nf4 = (int)(SLAB_FLOATS / 4);
    for (int q = idx; q < nf4; q += NB_TOKP * 256)
      s4[q] = make_float4(0.f, 0.f, 0.f, 0.f);
  }
}

// ---------------------------------------------------------------------------
// Final combine: slot sums + h-side terms + weight normalization.
// ---------------------------------------------------------------------------
__global__ __launch_bounds__(256) void kern_final(
    const float* __restrict__ h, const float* __restrict__ fi,
    const float* __restrict__ w, const float* __restrict__ acc,
    float* __restrict__ out) {
  const int t = threadIdx.x;
  const float sj2 = block_reduce_sum<4>(t < 64 ? acc[SLOT_J2 + t] : 0.0f);
  const float se  = block_reduce_sum<4>(t < 64 ? acc[SLOT_E + t] : 0.0f);
  const float slz = block_reduce_sum<4>(t < 64 ? acc[SLOT_LZ + t] : 0.0f);
  float hs = 0.0f, eh = 0.0f, ws = 0.0f;
  for (int idx = t; idx < LL * QQ; idx += 256) {
    const float hv = h[idx];
    hs += hv * hv;
    if (idx >= START * QQ) eh += fi[idx] * hv;
  }
  for (int idx = t; idx < MM; idx += 256) ws += w[idx];
  const float ths = block_reduce_sum<4>(hs);
  const float teh = block_reduce_sum<4>(eh);
  const float tws = block_reduce_sum<4>(ws);
  if (t == 0) {
    const float energy = teh + se;
    const float nll = slz / tws - energy;
    out[0] = nll + RGH * ths + RGJ * sj2;
    out[1] = nll;
  }
}

extern "C" void kernel_launch(void* const* d_in, const int* in_sizes, int n_in,
                              void* d_out, int out_size, void* d_ws, size_t ws_size,
                              hipStream_t stream) {
  const int*   Xtok = (const int*)  d_in[0];
  const float* wts  = (const float*)d_in[1];
  const float* fi   = (const float*)d_in[2];
  const float* fij  = (const float*)d_in[3];
  const float* h    = (const float*)d_in[4];
  const float* J    = (const float*)d_in[5];
  float* out  = (float*)d_out;
  float* acc  = (float*)d_ws;
  uint32_t* tokP = (uint32_t*)((char*)d_ws + TOKP_OFF);
  float* slab = (float*)((char*)d_ws + SLAB_OFF);

  if (ws_size >= WS_FULL) {
    kern_tokP<<<NB_TOKP, 256, 0, stream>>>(Xtok, tokP, slab, acc, 1);
    kern_mega<<<NB_P1 + NB_JS, BT, 0, stream>>>(J, fij, tokP, slab, acc);
    kern_logz_p2<<<dim3(NS, 8), 128, 0, stream>>>(slab, h, wts, acc);
    kern_final<<<1, 256, 0, stream>>>(h, fi, wts, acc, out);
  } else if (ws_size >= WS_TOK) {
    kern_tokP<<<NB_TOKP, 256, 0, stream>>>(Xtok, tokP, nullptr, acc, 0);
    kern_jsum<<<NB_JS, BT, 0, stream>>>(J, fij, acc);
    kern_logz_mono_t<<<dim3(NS, 1, 2), BT, 0, stream>>>(J, tokP, h, wts, acc);
    kern_final<<<1, 256, 0, stream>>>(h, fi, wts, acc, out);
  } else {
    hipMemsetAsync(d_ws, 0, 1024, stream);
    kern_jsum<<<NB_JS, BT, 0, stream>>>(J, fij, acc);
    kern_logz_mono_x<<<dim3(NS, 1, 2), BT, 0, stream>>>(J, Xtok, h, wts, acc);
    kern_final<<<1, 256, 0, stream>>>(h, fi, wts, acc, out);
  }
}

// Round 5
// 190.303 us; speedup vs baseline: 1.0258x; 1.0258x over previous
//
#include <hip/hip_runtime.h>
#include <cstdint>

// Problem constants (from the reference)
#define LL    200
#define QQ    21
#define MM    1024
#define START 133        // 2*L//3
#define NS    67         // L - START
#define RGH   0.01f
#define RGJ   0.01f

// ws layout:
//   [0, 1024)              : accumulator slots (3 x 64 fp32)
//   [1024, +TOKP)          : tokP packed tokens, 4 j per dword, [jq][n]
//   [TOKP end, +SLAB)      : logit slab [iI][a][n], atomic-accumulated
#define SLOT_J2  0
#define SLOT_E   64
#define SLOT_LZ  128
#define TOKP_W   52
#define TOKP_OFF 1024
#define TOKP_BYTES ((size_t)TOKP_W * MM * 4)
#define SLAB_OFF (TOKP_OFF + TOKP_BYTES)
#define SLAB_FLOATS ((size_t)NS * QQ * MM)
#define SLAB_BYTES (SLAB_FLOATS * 4)
#define WS_FULL (SLAB_OFF + SLAB_BYTES)
#define WS_TOK  SLAB_OFF

// LDS tile: a-major J[i, a, j0:j0+12, :], plane = 252 dwords (63 x 16B DMA).
// Gather per j: 10 x ds_read2_b32 (HAND-WRITTEN ASM — R3/R4's compiler-hint
// pairing never materialized; this guarantees it) + 1 x ds_read_b32:
// 11 LDS instrs instead of 21. Lanes differ only in b -> <=21 consecutive
// dwords -> conflict-free (measured 0 conflicts).
// NBUF=2 (depth-1 DMA pipeline): 2 x 21168 B = 42336 B/block ->
// 3 blocks/CU (2 z-paired p1 + 1 jsum filler, 24 waves/CU). The z-pair
// DMAs identical J tiles -> second block L2/L1-hot.
#define TJ 12
#define PLANE 252
#define TILE_FLOATS (QQ * PLANE)       // 5292 floats = 21168 B
#define NBUF 2
#define BT 512
#define NWAVE 8

// Balanced p1 schedule: flatten (site, j-quad) -> [0, Tz) cut into NB_R
// equal ranges (~11 quads); block bx = (range bx&255, z-half bx>>8).
#define NB_R  256
#define NB_P1 (2 * NB_R)               // 512
#define NB_JS 512
#define NB_TOKP 512

typedef const uint32_t __attribute__((address_space(1)))* gq_t;
typedef uint32_t __attribute__((address_space(3)))* lq_t;
typedef float __attribute__((address_space(3)))* lf3_t;
typedef float __attribute__((ext_vector_type(2))) f32x2;

template <int NW>
__device__ __forceinline__ float block_reduce_sum(float v) {
  __shared__ float sm[NW];
  #pragma unroll
  for (int off = 32; off > 0; off >>= 1) v += __shfl_down(v, off, 64);
  const int lane = threadIdx.x & 63;
  const int wv   = threadIdx.x >> 6;
  __syncthreads();
  if (lane == 0) sm[wv] = v;
  __syncthreads();
  float r = 0.0f;
  if (threadIdx.x == 0) {
    #pragma unroll
    for (int k = 0; k < NW; ++k) r += sm[k];
  }
  return r;  // valid in thread 0 only
}

// ---------------------------------------------------------------------------
// DMA one tile (21 a-planes) into LDS. Wave wv owns planes {wv, wv+8, wv+16}:
// waves 0-4 issue 3 global_load_lds, waves 5-7 issue 2; every wave has
// active lanes (nlanes >= 6), so per-wave vmem counts are exact.
// ---------------------------------------------------------------------------
__device__ __forceinline__ void dma_tile(
    const float* __restrict__ Ji, int j0, int rem, int wv, int lane,
    float* __restrict__ tile) {
  const int nlanes = (rem * QQ + 3) >> 2;      // 63 for rem=12
  if (lane < nlanes) {
    for (int a = wv; a < QQ; a += NWAVE) {
      const float* g = Ji + a * (LL * QQ) + j0 * QQ + lane * 4;
      __builtin_amdgcn_global_load_lds((gq_t)g, (lq_t)(tile + a * PLANE),
                                       16, 0, 0);
    }
  }
}

// ---------------------------------------------------------------------------
// Load the 3 packed token words covering tile at j0 (12 j's, j0 % 4 == 0).
// Always exactly 3 vmem loads. Fully-fake tiles reload tile-0's words.
// ---------------------------------------------------------------------------
template <int USET>
__device__ __forceinline__ void tok_words(
    const uint32_t* __restrict__ tokP, const int* __restrict__ Xtok,
    int j0, int jbeg, int jend, int n, uint32_t (&tw)[3]) {
  const int wbase = ((j0 < jend) ? j0 : jbeg) >> 2;
  #pragma unroll
  for (int wi = 0; wi < 3; ++wi) {
    int wq = wbase + wi;
    if constexpr (USET) {
      tw[wi] = tokP[wq * MM + n];        // words 50/51 = pad, never consumed
    } else {
      if (wq >= LL / 4) wq -= (LL / 4 - 1);   // keep in-bounds, distinct
      const int4 x = *reinterpret_cast<const int4*>(Xtok + n * LL + 4 * wq);
      tw[wi] = (uint32_t)x.x | ((uint32_t)x.y << 8)
             | ((uint32_t)x.z << 16) | ((uint32_t)x.w << 24);
    }
  }
}

// ---------------------------------------------------------------------------
// Guaranteed-paired gather for one j: 10 ds_read2_b32 (offset0:0 offset1:252)
// + 1 ds_read_b32, in two 5-pair batches (caps live VGPRs). Rule #18:
// consumption only after in-asm lgkmcnt(0) + sched_barrier(0). asm volatile
// order keeps reads before their wait.
// ---------------------------------------------------------------------------
#define RD2(dst, addr) \
  asm volatile("ds_read2_b32 %0, %1 offset0:0 offset1:252" \
               : "=&v"(dst) : "v"((lf3_t)(addr)))

__device__ __forceinline__ void gather_j(
    const float* __restrict__ tile, int bo, float (&lg)[QQ]) {
  const float* p = tile + bo;
  f32x2 r0, r1, r2, r3, r4;
  RD2(r0, p);
  RD2(r1, p + 504);
  RD2(r2, p + 1008);
  RD2(r3, p + 1512);
  RD2(r4, p + 2016);
  asm volatile("s_waitcnt lgkmcnt(0)" ::: "memory");
  __builtin_amdgcn_sched_barrier(0);
  lg[0] += r0.x; lg[1] += r0.y; lg[2] += r1.x; lg[3] += r1.y;
  lg[4] += r2.x; lg[5] += r2.y; lg[6] += r3.x; lg[7] += r3.y;
  lg[8] += r4.x; lg[9] += r4.y;
  f32x2 s0, s1, s2, s3, s4; float t20;
  RD2(s0, p + 2520);
  RD2(s1, p + 3024);
  RD2(s2, p + 3528);
  RD2(s3, p + 4032);
  RD2(s4, p + 4536);
  asm volatile("ds_read_b32 %0, %1 offset:20160"      // plane 20 (5040 dw)
               : "=&v"(t20) : "v"((lf3_t)p));
  asm volatile("s_waitcnt lgkmcnt(0)" ::: "memory");
  __builtin_amdgcn_sched_barrier(0);
  lg[10] += s0.x; lg[11] += s0.y; lg[12] += s1.x; lg[13] += s1.y;
  lg[14] += s2.x; lg[15] += s2.y; lg[16] += s3.x; lg[17] += s3.y;
  lg[18] += s4.x; lg[19] += s4.y; lg[20] += t20;
}

// ---------------------------------------------------------------------------
// One pipelined segment, NBUF=2 depth-1 DMA / depth-2 tokens.
// Steady iteration: [dma(s+1)] [SB] [tok(s+2)] [gather s] [unpack bo(s+1)]
// [vmcnt(3): drains all dma + tok(s+1), keeps tok(s+2) in flight] [barrier].
// vmcnt(3) is uniform across waves (it drains ALL dma regardless of 3-vs-2)
// and correct for the last iteration (no dma issued).
// ---------------------------------------------------------------------------
template <int USET>
__device__ __forceinline__ void logz_seg(
    const float* __restrict__ Ji, const uint32_t* __restrict__ tokP,
    const int* __restrict__ Xtok, int jbeg, int jend, int n,
    float (*lds)[TILE_FLOATS], float (&lg)[QQ], int wv, int lane) {
  const int ntiles = (jend - jbeg + TJ - 1) / TJ;   // >= 1
  uint32_t tw0[3], twc[3], twn[3];
  int bo[TJ];

  dma_tile(Ji, jbeg, min(TJ, jend - jbeg), wv, lane, lds[0]);
  tok_words<USET>(tokP, Xtok, jbeg, jbeg, jend, n, tw0);
  tok_words<USET>(tokP, Xtok, jbeg + TJ, jbeg, jend, n, twc);
  #pragma unroll
  for (int k = 0; k < TJ; ++k)
    bo[k] = k * QQ + (int)((tw0[k >> 2] >> ((k & 3) * 8)) & 0xFF);
  asm volatile("s_waitcnt vmcnt(0)" ::: "memory");
  __builtin_amdgcn_s_barrier();
  __builtin_amdgcn_sched_barrier(0);

  int cur = 0;
  for (int s = 0; s < ntiles; ++s) {
    const int j0  = jbeg + s * TJ;
    const int rem = min(TJ, jend - j0);
    if (s + 1 < ntiles) {               // block-uniform branch
      const int j1 = j0 + TJ;
      dma_tile(Ji, j1, min(TJ, jend - j1), wv, lane, lds[cur ^ 1]);
    }
    __builtin_amdgcn_sched_barrier(0);  // pin: dma issued before tok loads
    tok_words<USET>(tokP, Xtok, j0 + 2 * TJ, jbeg, jend, n, twn);
    #pragma unroll
    for (int jl = 0; jl < TJ; ++jl) {
      if (jl >= rem) break;             // block-uniform
      gather_j(lds[cur], bo[jl], lg);
    }
    #pragma unroll
    for (int k = 0; k < TJ; ++k)
      bo[k] = k * QQ + (int)((twc[k >> 2] >> ((k & 3) * 8)) & 0xFF);
    #pragma unroll
    for (int wi = 0; wi < 3; ++wi) twc[wi] = twn[wi];
    asm volatile("s_waitcnt vmcnt(3)" ::: "memory");
    __builtin_amdgcn_s_barrier();
    __builtin_amdgcn_sched_barrier(0);
    cur ^= 1;
  }
}

// ---------------------------------------------------------------------------
// p1 block: balanced quad-schedule per z-half. Range r owns quads
// [r*Tz/NB_R, (r+1)*Tz/NB_R); spans <=2 sites; atomic-flush into slab.
// Blocks (r, z=0) and (r, z=1) co-reside on a CU and DMA identical J tiles.
// ---------------------------------------------------------------------------
__device__ __forceinline__ void p1_block(
    const float* __restrict__ J, const uint32_t* __restrict__ tokP,
    float* __restrict__ slab, int bx, float (*lds)[TILE_FLOATS]) {
  const int t = threadIdx.x, lane = t & 63, wv = t >> 6;
  const int r = bx & (NB_R - 1);
  const int z = bx >> 8;

  int Tz = 0;                          // constant-folds
  #pragma unroll
  for (int s2 = 0; s2 < NS; ++s2) Tz += (START + s2 + 3) >> 2;

  int g  = (r * Tz) / NB_R;
  const int g1 = ((r + 1) * Tz) / NB_R;
  int iI = 0, pref = 0;
  while (pref + ((START + iI + 3) >> 2) <= g) {
    pref += (START + iI + 3) >> 2;
    ++iI;
  }
  int qlo = g - pref;

  float lg[QQ];
  #pragma unroll
  for (int a = 0; a < QQ; ++a) lg[a] = 0.0f;

  while (g < g1) {
    const int i    = START + iI;
    const int qcap = (i + 3) >> 2;
    int qhi = qlo + (g1 - g);
    if (qhi > qcap) qhi = qcap;
    const int jbeg = qlo * 4;
    int jend = qhi * 4; if (jend > i) jend = i;
    const int n = z * BT + t;
    const float* Ji = J + (size_t)i * (QQ * LL * QQ);

    logz_seg<1>(Ji, tokP, nullptr, jbeg, jend, n, lds, lg, wv, lane);

    float* dst = slab + ((size_t)iI * QQ) * MM + n;
    #pragma unroll
    for (int a = 0; a < QQ; ++a) { atomicAdd(dst + a * MM, lg[a]); lg[a] = 0.0f; }

    g += qhi - qlo;
    qlo = 0; ++iI;
  }
}

// ---------------------------------------------------------------------------
// jsum body: sum(J^2) stream + sum(J*fij) prefix rows, grid-strided by jb.
// ---------------------------------------------------------------------------
__device__ __forceinline__ void jsum_body(
    const float* __restrict__ J, const float* __restrict__ fij,
    float* __restrict__ acc, int jb) {
  const int t = threadIdx.x;
  const float4* __restrict__ J4 = (const float4*)J;
  float j2 = 0.0f;
  for (int f = jb * BT + t; f < (LL * QQ * LL * QQ / 4); f += NB_JS * BT) {
    const float4 v = J4[f];
    j2 += v.x * v.x + v.y * v.y + v.z * v.z + v.w * v.w;
  }
  float e = 0.0f;
  for (int r = jb; r < NS * QQ; r += NB_JS) {
    const int iI = r / QQ;
    const int a  = r - iI * QQ;
    const int i  = START + iI;
    const size_t base = (size_t)i * (QQ * LL * QQ) + (size_t)a * (LL * QQ);
    const float4* __restrict__ Jb = (const float4*)(J + base);
    const float4* __restrict__ Fb = (const float4*)(fij + base);
    const int lim  = i * QQ;
    const int lim4 = lim >> 2;
    for (int f = t; f < lim4; f += BT) {
      const float4 v = Jb[f], u = Fb[f];
      e += v.x * u.x + v.y * u.y + v.z * u.z + v.w * u.w;
    }
    const int rem = lim & 3;
    if (t < rem) {
      const int p = lim4 * 4 + t;
      e += (J + base)[p] * (fij + base)[p];
    }
  }
  const float tj2 = block_reduce_sum<NWAVE>(j2);
  const float te  = block_reduce_sum<NWAVE>(e);
  if (t == 0) {
    atomicAdd(acc + SLOT_J2 + (jb & 63), tj2);
    atomicAdd(acc + SLOT_E  + (jb & 63), te);
  }
}

// ---------------------------------------------------------------------------
// Fused kernel: blocks [0, NB_P1) = p1 (2 z-paired per CU), then jsum
// fillers on the 3rd block slot + makespan tail. launch_bounds(512,6)
// enforces 24 waves/CU (VGPR <= ~85).
// ---------------------------------------------------------------------------
__global__ __launch_bounds__(BT, 6) void kern_mega(
    const float* __restrict__ J, const float* __restrict__ fij,
    const uint32_t* __restrict__ tokP, float* __restrict__ slab,
    float* __restrict__ acc) {
  __shared__ float lds[NBUF][TILE_FLOATS];
  const int bx = blockIdx.x;
  if (bx < NB_P1) p1_block(J, tokP, slab, bx, lds);
  else            jsum_body(J, fij, acc, bx - NB_P1);
}

// ---------------------------------------------------------------------------
// Fallback (ws too small for slab): full-range mono blocks with in-kernel
// logsumexp. Grid (NS, 1, 2), z = blockIdx.z.
// ---------------------------------------------------------------------------
template <int USET>
__device__ __forceinline__ void mono_body(
    const float* __restrict__ J, const uint32_t* __restrict__ tokP,
    const int* __restrict__ Xtok, const float* __restrict__ h,
    const float* __restrict__ w, float* __restrict__ acc,
    float (*lds)[TILE_FLOATS]) {
  const int iI = blockIdx.x;
  const int i  = START + iI;
  const int t = threadIdx.x, lane = t & 63, wv = t >> 6;
  const int n = blockIdx.z * BT + t;
  float lg[QQ];
  #pragma unroll
  for (int a = 0; a < QQ; ++a) lg[a] = 0.0f;
  logz_seg<USET>(J + (size_t)i * (QQ * LL * QQ), tokP, Xtok, 0, i, n,
                 lds, lg, wv, lane);
  const float* hi = h + i * QQ;
  float mx = -3.0e38f;
  #pragma unroll
  for (int a = 0; a < QQ; ++a) { lg[a] += hi[a]; mx = fmaxf(mx, lg[a]); }
  float sme = 0.0f;
  #pragma unroll
  for (int a = 0; a < QQ; ++a) sme += expf(lg[a] - mx);
  const float contrib = w[n] * (mx + logf(sme));
  const float tot = block_reduce_sum<NWAVE>(contrib);
  if (t == 0) atomicAdd(acc + SLOT_LZ + (iI & 63), tot);
}

__global__ __launch_bounds__(BT) void kern_logz_mono_t(
    const float* __restrict__ J, const uint32_t* __restrict__ tokP,
    const float* __restrict__ h, const float* __restrict__ w,
    float* __restrict__ acc) {
  __shared__ float lds[NBUF][TILE_FLOATS];
  mono_body<1>(J, tokP, nullptr, h, w, acc, lds);
}

__global__ __launch_bounds__(BT) void kern_logz_mono_x(
    const float* __restrict__ J, const int* __restrict__ Xtok,
    const float* __restrict__ h, const float* __restrict__ w,
    float* __restrict__ acc) {
  __shared__ float lds[NBUF][TILE_FLOATS];
  mono_body<0>(J, nullptr, Xtok, h, w, acc, lds);
}

__global__ __launch_bounds__(BT) void kern_jsum(
    const float* __restrict__ J, const float* __restrict__ fij,
    float* __restrict__ acc) {
  jsum_body(J, fij, acc, blockIdx.x);
}

// ---------------------------------------------------------------------------
// Phase 2: slab + h -> logsumexp -> weighted sum (fence-free).
// ---------------------------------------------------------------------------
__global__ __launch_bounds__(128) void kern_logz_p2(
    const float* __restrict__ slab, const float* __restrict__ h,
    const float* __restrict__ w, float* __restrict__ acc) {
  const int iI = blockIdx.x;
  const int n  = blockIdx.y * 128 + threadIdx.x;
  const float* s0 = slab + ((size_t)iI * QQ) * MM + n;
  const float* hi = h + (START + iI) * QQ;
  float lg[QQ];
  float mx = -3.0e38f;
  #pragma unroll
  for (int a = 0; a < QQ; ++a) {
    lg[a] = s0[a * MM] + hi[a];
    mx = fmaxf(mx, lg[a]);
  }
  float sme = 0.0f;
  #pragma unroll
  for (int a = 0; a < QQ; ++a) sme += expf(lg[a] - mx);
  float v = w[n] * (mx + logf(sme));
  #pragma unroll
  for (int off = 32; off > 0; off >>= 1) v += __shfl_down(v, off, 64);
  __shared__ float sm[2];
  if ((threadIdx.x & 63) == 0) sm[threadIdx.x >> 6] = v;
  __syncthreads();
  if (threadIdx.x == 0)
    atomicAdd(acc + SLOT_LZ + ((iI * 8 + blockIdx.y) & 63), sm[0] + sm[1]);
}

// ---------------------------------------------------------------------------
// Token packing + accumulator/slab zeroing.
// ---------------------------------------------------------------------------
__global__ __launch_bounds__(256) void kern_tokP(
    const int* __restrict__ X, uint32_t* __restrict__ tokP,
    float* __restrict__ slab, float* __restrict__ acc, int zslab) {
  const int idx = blockIdx.x * 256 + threadIdx.x;
  if (blockIdx.x == 0) acc[threadIdx.x] = 0.0f;
  if (idx < (LL / 4) * MM) {
    const int jq = idx / MM;
    const int n  = idx - jq * MM;
    const int4 x = *reinterpret_cast<const int4*>(X + n * LL + 4 * jq);
    tokP[idx] = (uint32_t)x.x | ((uint32_t)x.y << 8)
              | ((uint32_t)x.z << 16) | ((uint32_t)x.w << 24);
  }
  if (zslab) {
    float4* s4 = (float4*)slab;
    const int nf4 = (int)(SLAB_FLOATS / 4);
    for (int q = idx; q < nf4; q += NB_TOKP * 256)
      s4[q] = make_float4(0.f, 0.f, 0.f, 0.f);
  }
}

// ---------------------------------------------------------------------------
// Final combine: slot sums + h-side terms + weight normalization.
// ---------------------------------------------------------------------------
__global__ __launch_bounds__(256) void kern_final(
    const float* __restrict__ h, const float* __restrict__ fi,
    const float* __restrict__ w, const float* __restrict__ acc,
    float* __restrict__ out) {
  const int t = threadIdx.x;
  const float sj2 = block_reduce_sum<4>(t < 64 ? acc[SLOT_J2 + t] : 0.0f);
  const float se  = block_reduce_sum<4>(t < 64 ? acc[SLOT_E + t] : 0.0f);
  const float slz = block_reduce_sum<4>(t < 64 ? acc[SLOT_LZ + t] : 0.0f);
  float hs = 0.0f, eh = 0.0f, ws = 0.0f;
  for (int idx = t; idx < LL * QQ; idx += 256) {
    const float hv = h[idx];
    hs += hv * hv;
    if (idx >= START * QQ) eh += fi[idx] * hv;
  }
  for (int idx = t; idx < MM; idx += 256) ws += w[idx];
  const float ths = block_reduce_sum<4>(hs);
  const float teh = block_reduce_sum<4>(eh);
  const float tws = block_reduce_sum<4>(ws);
  if (t == 0) {
    const float energy = teh + se;
    const float nll = slz / tws - energy;
    out[0] = nll + RGH * ths + RGJ * sj2;
    out[1] = nll;
  }
}

extern "C" void kernel_launch(void* const* d_in, const int* in_sizes, int n_in,
                              void* d_out, int out_size, void* d_ws, size_t ws_size,
                              hipStream_t stream) {
  const int*   Xtok = (const int*)  d_in[0];
  const float* wts  = (const float*)d_in[1];
  const float* fi   = (const float*)d_in[2];
  const float* fij  = (const float*)d_in[3];
  const float* h    = (const float*)d_in[4];
  const float* J    = (const float*)d_in[5];
  float* out  = (float*)d_out;
  float* acc  = (float*)d_ws;
  uint32_t* tokP = (uint32_t*)((char*)d_ws + TOKP_OFF);
  float* slab = (float*)((char*)d_ws + SLAB_OFF);

  if (ws_size >= WS_FULL) {
    kern_tokP<<<NB_TOKP, 256, 0, stream>>>(Xtok, tokP, slab, acc, 1);
    kern_mega<<<NB_P1 + NB_JS, BT, 0, stream>>>(J, fij, tokP, slab, acc);
    kern_logz_p2<<<dim3(NS, 8), 128, 0, stream>>>(slab, h, wts, acc);
    kern_final<<<1, 256, 0, stream>>>(h, fi, wts, acc, out);
  } else if (ws_size >= WS_TOK) {
    kern_tokP<<<NB_TOKP, 256, 0, stream>>>(Xtok, tokP, nullptr, acc, 0);
    kern_jsum<<<NB_JS, BT, 0, stream>>>(J, fij, acc);
    kern_logz_mono_t<<<dim3(NS, 1, 2), BT, 0, stream>>>(J, tokP, h, wts, acc);
    kern_final<<<1, 256, 0, stream>>>(h, fi, wts, acc, out);
  } else {
    hipMemsetAsync(d_ws, 0, 1024, stream);
    kern_jsum<<<NB_JS, BT, 0, stream>>>(J, fij, acc);
    kern_logz_mono_x<<<dim3(NS, 1, 2), BT, 0, stream>>>(J, Xtok, h, wts, acc);
    kern_final<<<1, 256, 0, stream>>>(h, fi, wts, acc, out);
  }
}